// Round 1
// baseline (161.833 us; speedup 1.0000x reference)
//
#include <hip/hip_runtime.h>
#include <hip/hip_bf16.h>

// out[b, l, c] = data[(cycle_index[b] % CYC + l) % CYC, c]
// B=4096, L=720, C=64 fp32. Pure streaming-write kernel (~755MB out).
// Block = 256 threads = 16 l-values x 16 float4 (full C row).
// Wave of 64 lanes stores 1KB contiguous -> perfectly coalesced.

#define CHANNELS 64      // C (floats)  -> 16 float4 per row
#define C4       16      // C / 4
#define CYC      168     // cycle length
#define LPB      16      // l-values per block

__global__ __launch_bounds__(256) void recurrent_cycle_kernel(
    const int* __restrict__ cycle_index,
    const float4* __restrict__ data4,   // [CYC][C4]
    float4* __restrict__ out4,          // [B][L][C4]
    int L, int chunks)                  // chunks = ceil(L / LPB)
{
    const int blk = blockIdx.x;
    const int b   = blk / chunks;
    const int lc  = blk - b * chunks;

    const int t   = threadIdx.x;
    const int l   = lc * LPB + (t >> 4);
    if (l >= L) return;
    const int c4  = t & 15;

    const int start = cycle_index[b] % CYC;     // per-reference: mod first
    int src = start + l;                        // < CYC + L
    src %= CYC;

    const float4 v = data4[src * C4 + c4];
    out4[((size_t)b * L + l) * C4 + c4] = v;
}

extern "C" void kernel_launch(void* const* d_in, const int* in_sizes, int n_in,
                              void* d_out, int out_size, void* d_ws, size_t ws_size,
                              hipStream_t stream) {
    const int*   cycle_index = (const int*)d_in[0];
    // d_in[1] is output_len (scalar on device) -- we derive L from out_size instead.
    const float* data        = (const float*)d_in[2];

    const int B = in_sizes[0];                 // 4096
    const int L = out_size / (B * CHANNELS);   // 720

    const int chunks = (L + LPB - 1) / LPB;    // 45
    const int grid   = B * chunks;             // 184320

    recurrent_cycle_kernel<<<grid, 256, 0, stream>>>(
        cycle_index,
        (const float4*)data,
        (float4*)d_out,
        L, chunks);
}

// Round 3
// 150.455 us; speedup vs baseline: 1.0756x; 1.0756x over previous
//
#include <hip/hip_runtime.h>
#include <hip/hip_bf16.h>

// out[b, l, c] = data[(cycle_index[b] % CYC + l) % CYC, c]
// B=4096, L=720, C=64 fp32. ~755MB pure streaming writes -> write-BW bound.
// R2: same as R1 but use clang ext_vector float4 so
// __builtin_nontemporal_store accepts it (HIP_vector_type is a class).

typedef float f4_t __attribute__((ext_vector_type(4)));

#define B_      4096
#define L_      720
#define C4_     16        // 64 floats / 4
#define CYC_    168
#define LPB_    16        // l-values per chunk
#define CHUNKS_ (L_ / LPB_)          // 45 (exact)
#define NCHUNK_ (B_ * CHUNKS_)       // 184320

__global__ __launch_bounds__(256) void rc_kernel_fixed(
    const int* __restrict__ cycle_index,
    const f4_t* __restrict__ data4,    // [CYC][C4]
    f4_t* __restrict__ out4)           // [B][L][C4]
{
    const int t    = threadIdx.x;
    const int lofs = t >> 4;            // 0..15
    const int c4   = t & 15;            // 0..15

    for (int chunk = blockIdx.x; chunk < NCHUNK_; chunk += gridDim.x) {
        const int b  = chunk / CHUNKS_;          // const divisor -> magic mul
        const int lc = chunk - b * CHUNKS_;
        const int l  = lc * LPB_ + lofs;

        const int start = cycle_index[b] % CYC_; // uniform per iteration
        int src = start + l;                     // < CYC_ + L_
        src %= CYC_;                             // const divisor -> magic mul

        const f4_t v = data4[src * C4_ + c4];    // L1/L2-resident (43KB table)
        __builtin_nontemporal_store(
            v, &out4[((size_t)b * L_ + l) * C4_ + c4]);
    }
}

// Generic fallback (any B/L), grid-stride + NT store.
__global__ __launch_bounds__(256) void rc_kernel_generic(
    const int* __restrict__ cycle_index,
    const f4_t* __restrict__ data4,
    f4_t* __restrict__ out4,
    int L, int chunks, int nchunk_total)
{
    const int t    = threadIdx.x;
    const int lofs = t >> 4;
    const int c4   = t & 15;

    for (int chunk = blockIdx.x; chunk < nchunk_total; chunk += gridDim.x) {
        const int b  = chunk / chunks;
        const int lc = chunk - b * chunks;
        const int l  = lc * LPB_ + lofs;
        if (l >= L) continue;

        const int start = cycle_index[b] % CYC_;
        int src = start + l;
        src %= CYC_;

        const f4_t v = data4[src * C4_ + c4];
        __builtin_nontemporal_store(
            v, &out4[((size_t)b * (size_t)L + l) * C4_ + c4]);
    }
}

extern "C" void kernel_launch(void* const* d_in, const int* in_sizes, int n_in,
                              void* d_out, int out_size, void* d_ws, size_t ws_size,
                              hipStream_t stream) {
    const int*   cycle_index = (const int*)d_in[0];
    const float* data        = (const float*)d_in[2];

    const int B = in_sizes[0];
    const int L = out_size / (B * 64);

    const int grid = 2048;  // 256 CU x 8 blocks, grid-stride

    if (B == B_ && L == L_) {
        rc_kernel_fixed<<<grid, 256, 0, stream>>>(
            cycle_index, (const f4_t*)data, (f4_t*)d_out);
    } else {
        const int chunks = (L + LPB_ - 1) / LPB_;
        const int nchunk = B * chunks;
        rc_kernel_generic<<<grid, 256, 0, stream>>>(
            cycle_index, (const f4_t*)data, (f4_t*)d_out,
            L, chunks, nchunk);
    }
}